// Round 17
// baseline (176.976 us; speedup 1.0000x reference)
//
#include <hip/hip_runtime.h>
#include <hip/hip_bf16.h>

constexpr int B  = 128;
constexpr int LQ = 128;
constexpr int LS = 256;
constexpr int D  = 1024;
constexpr int SD = 256;
constexpr float EPS = 1e-8f;

typedef __attribute__((ext_vector_type(8))) __bf16 bf16x8;
typedef __attribute__((ext_vector_type(4))) float f32x4;

__device__ inline ushort f2bf(float f) {
    union { float f; uint u; } v{f};
    uint r = v.u + 0x7fffu + ((v.u >> 16) & 1u);   // RNE
    return (ushort)(r >> 16);
}
__device__ inline float bf2f(ushort u) {
    union { uint u; float f; } v{(uint)u << 16};
    return v.f;
}
__device__ inline uint4 pack8(float4 a, float4 b) {
    union { ushort us[8]; uint4 u4; } r;
    r.us[0]=f2bf(a.x); r.us[1]=f2bf(a.y); r.us[2]=f2bf(a.z); r.us[3]=f2bf(a.w);
    r.us[4]=f2bf(b.x); r.us[5]=f2bf(b.y); r.us[6]=f2bf(b.z); r.us[7]=f2bf(b.w);
    return r.u4;
}
// 128B-row LDS tiles (64 bf16): XOR-swizzle bank fix
__device__ inline int swz(int row, int kbyte) {
    return row * 128 + (kbyte ^ ((row & 7) << 4));
}
__device__ inline bf16x8 lds_frag(const ushort* base, int row, int kk, int lane) {
    int kbyte = kk * 64 + (lane >> 4) * 16;
    return *(const bf16x8*)((const char*)base + swz(row, kbyte));
}
// 512B-row LDS tiles (256 bf16): same XOR pattern
__device__ inline int swz512(int row, int kbyte) {
    return row * 512 + (kbyte ^ ((row & 7) << 4));
}
__device__ inline f32x4 mfma16(bf16x8 a, bf16x8 b, f32x4 c) {
    return __builtin_amdgcn_mfma_f32_16x16x32_bf16(a, b, c, 0, 0, 0);
}

// =====================================================================
// Wb (bf16) <- W fp32
// =====================================================================
__global__ __launch_bounds__(256) void wconv_kernel(
    const float* __restrict__ W, ushort* __restrict__ Wb)
{
    size_t i = ((size_t)blockIdx.x * 256 + threadIdx.x) * 8;
    float4 a = *(const float4*)(W + i);
    float4 b = *(const float4*)(W + i + 4);
    *(uint4*)(Wb + i) = pack8(a, b);
}

// =====================================================================
// qmpack: qm_tiled[b][kt][r][kc] (bf16, 16KB tiles) = q*m.
// Reads contiguous; writes 16B chunks into tile layout.
// =====================================================================
__global__ __launch_bounds__(256) void qmpack_kernel(
    const float* __restrict__ query, const float* __restrict__ mat,
    ushort* __restrict__ qmt)
{
    size_t i8 = ((size_t)blockIdx.x * 256 + threadIdx.x) * 8;
    float4 q1 = *(const float4*)(query + i8), q2 = *(const float4*)(query + i8 + 4);
    float4 m1 = *(const float4*)(mat + i8),   m2 = *(const float4*)(mat + i8 + 4);
    float4 p1{q1.x*m1.x, q1.y*m1.y, q1.z*m1.z, q1.w*m1.w};
    float4 p2{q2.x*m2.x, q2.y*m2.y, q2.z*m2.z, q2.w*m2.w};
    const int b  = (int)(i8 >> 17);
    const int rem = (int)(i8 & 131071);
    const int r  = rem >> 10;
    const int k  = rem & 1023;
    const int kt = k >> 6, kc = k & 63;
    *(uint4*)(qmt + ((size_t)(b * 16 + kt) * 8192 + r * 64 + kc)) = pack8(p1, p2);
}

// =====================================================================
// cpack: ctx_tiled[(b*2+sh)][kt][sr][kc] (bf16, 16KB tiles) = ctx.
// =====================================================================
__global__ __launch_bounds__(256) void cpack_kernel(
    const float* __restrict__ ctx, ushort* __restrict__ ctxt)
{
    size_t i8 = ((size_t)blockIdx.x * 256 + threadIdx.x) * 8;
    float4 c1 = *(const float4*)(ctx + i8), c2 = *(const float4*)(ctx + i8 + 4);
    const int b  = (int)(i8 >> 18);
    const int rem = (int)(i8 & 262143);
    const int s  = rem >> 10;
    const int k  = rem & 1023;
    const int sh = s >> 7, sr = s & 127;
    const int kt = k >> 6, kc = k & 63;
    *(uint4*)(ctxt + ((size_t)((b * 2 + sh) * 16 + kt) * 8192 + sr * 64 + kc)) = pack8(c1, c2);
}

// =====================================================================
// gemmA: per block (b, s-half): S = leaky(qm . ctx^T); col-l2norm over
// q (all 128 in-block); E = exp(S*inv*smooth) bf16.
// ALL loads are contiguous 16KB-tile sweeps of qm_tiled/ctx_tiled
// (the DRAM-pattern fix). Chunk c of a tile = element offset c*8
// (r16 bug: used c*16 -> wrong operands; fixed here).
// Grid 256 = (b x 2 sh), XCD-swizzled. 512 thr, 8 waves 2q x 4s.
// BM=128 BN=128 BK=64, dbuf 64 KB -> 2 blocks/CU.
// =====================================================================
__global__ __launch_bounds__(512, 2) void gemmA_kernel(
    const ushort* __restrict__ qmt, const ushort* __restrict__ ctxt,
    const int* __restrict__ smooth_p, ushort* __restrict__ E)
{
    const int bid = blockIdx.x;            // 256 blocks
    const int xcd = bid & 7, idx = bid >> 3;
    const int b  = xcd * 16 + (idx >> 1);
    const int sh = idx & 1;
    const int n0 = sh * 128;
    __shared__ ushort SH[4][128 * 64];     // As0,As1,Bs0,Bs1 (64 KB)
    __shared__ float colssP[2][128];
    __shared__ float invsm[128];
    ushort* Et = &SH[0][0];                // epilogue alias: 128 x 136

    const int t = threadIdx.x;
    const int wv = t >> 6, l = t & 63;
    const int wq = wv >> 2, wsv = wv & 3;

    const ushort* Ab = qmt  + (size_t)b * 16 * 8192;            // [kt][8192]
    const ushort* Bb = ctxt + (size_t)(b * 2 + sh) * 16 * 8192; // [kt][8192]

    // chunk coords: thread t owns chunks t and t+512 of each 16KB tile
    const int ra = t >> 3,        ka = (t & 7) * 8;     // chunk t
    const int rb = (t >> 3) + 64, kb = (t & 7) * 8;     // chunk t+512

    f32x4 acc[4][2] = {};
    uint4 a0, a1, b0, b1;

    auto loadT = [&](int kt) {
        const ushort* ap = Ab + (size_t)kt * 8192;
        const ushort* bp = Bb + (size_t)kt * 8192;
        a0 = *(const uint4*)(ap + t * 8);
        a1 = *(const uint4*)(ap + (t + 512) * 8);
        b0 = *(const uint4*)(bp + t * 8);
        b1 = *(const uint4*)(bp + (t + 512) * 8);
    };
    auto storeT = [&](int buf) {
        *(uint4*)((char*)&SH[buf][0] + swz(ra, ka * 2))     = a0;
        *(uint4*)((char*)&SH[buf][0] + swz(rb, kb * 2))     = a1;
        *(uint4*)((char*)&SH[2 + buf][0] + swz(ra, ka * 2)) = b0;
        *(uint4*)((char*)&SH[2 + buf][0] + swz(rb, kb * 2)) = b1;
    };
    auto mfmaT = [&](int buf) {
#pragma unroll
        for (int kk = 0; kk < 2; ++kk) {
            bf16x8 bfr0 = lds_frag(&SH[2 + buf][0], wsv * 32 + (l & 15), kk, l);
            bf16x8 bfr1 = lds_frag(&SH[2 + buf][0], wsv * 32 + 16 + (l & 15), kk, l);
#pragma unroll
            for (int i = 0; i < 4; ++i) {
                bf16x8 af = lds_frag(&SH[buf][0], wq * 64 + i * 16 + (l & 15), kk, l);
                acc[i][0] = mfma16(af, bfr0, acc[i][0]);
                acc[i][1] = mfma16(af, bfr1, acc[i][1]);
            }
        }
    };

    loadT(0);
    storeT(0);
    __syncthreads();
    int cur = 0;
#pragma unroll 1
    for (int ks = 0; ks < 15; ++ks) {
        loadT(ks + 1);
        mfmaT(cur);
        storeT(cur ^ 1);
        __syncthreads();
        cur ^= 1;
    }
    mfmaT(cur);

    // ---- epilogue: leaky + col sumsq -> invsm -> E = exp ----
#pragma unroll
    for (int n = 0; n < 2; ++n) {
        float csum = 0.f;
#pragma unroll
        for (int i = 0; i < 4; ++i)
#pragma unroll
            for (int r = 0; r < 4; ++r) {
                float v = acc[i][n][r];
                v = v >= 0.f ? v : 0.1f * v;
                acc[i][n][r] = v;
                csum += v * v;
            }
        csum += __shfl_xor(csum, 16);
        csum += __shfl_xor(csum, 32);
        if (l < 16) colssP[wq][wsv * 32 + n * 16 + l] = csum;
    }
    __syncthreads();   // all MFMA reads done -> SH reusable as Et
    const float sm = (float)(*smooth_p);
    if (t < 128) invsm[t] = sm / (sqrtf(colssP[0][t] + colssP[1][t]) + EPS);
    __syncthreads();
#pragma unroll
    for (int n = 0; n < 2; ++n) {
        const float invc = invsm[wsv * 32 + n * 16 + (l & 15)];
#pragma unroll
        for (int i = 0; i < 4; ++i)
#pragma unroll
            for (int r = 0; r < 4; ++r) {
                int row = wq * 64 + i * 16 + (l >> 4) * 4 + r;
                Et[row * 136 + wsv * 32 + n * 16 + (l & 15)] =
                    f2bf(__expf(acc[i][n][r] * invc));
            }
    }
    __syncthreads();
    // coalesced E store
    ushort* Eg = E + (size_t)b * LQ * LS + n0;
#pragma unroll
    for (int j = 0; j < 4; ++j) {
        int c = t + j * 512;
        int row = c >> 4, s8 = (c & 15) * 8;
        *(uint4*)(Eg + (size_t)row * LS + s8) = *(const uint4*)(Et + row * 136 + s8);
    }
}

// =====================================================================
// pv: wctx[128q][512d-half] = (E . ctx^T) * (1/rowsum(E)); rowss partials.
// Grid 256 = (b x 2 dh), XCD-swizzled. 512 thr, 8 waves 2q x 4d.
// B staged from ctx_tiled (bf16, contiguous tile reads) via in-LDS
// transpose into padded Bs[64][264].
// =====================================================================
__global__ __launch_bounds__(512, 2) void pv_kernel(
    const ushort* __restrict__ E, const ushort* __restrict__ ctxt,
    ushort* __restrict__ wctx, float* __restrict__ rowssP)
{
    const int bid = blockIdx.x;
    const int xcd = bid & 7, idx = bid >> 3;
    const int b  = xcd * 16 + (idx >> 1);
    const int dh = idx & 1;
    const int dglob0 = dh * 512;

    __shared__ ushort Es[128 * 256];       // 64 KB swz512
    __shared__ ushort Bs[64 * 264];        // 33 KB padded [d][s+8]
    __shared__ float rsumL[128];
    __shared__ float rinv[128];
    __shared__ float rowssL[128][4];

    const int t = threadIdx.x;
    const int wv = t >> 6, l = t & 63;
    const int wq = wv >> 2, wd = wv & 3;

    // ---- stage E (128q x 256s) + per-row exp sums ----
    const ushort* Eb = E + (size_t)b * LQ * LS;
    const int cc = t & 31, rr = t >> 5;
    float part[8];
#pragma unroll
    for (int p = 0; p < 8; ++p) {
        int row = rr + p * 16;
        uint4 v = *(const uint4*)(Eb + (size_t)row * LS + cc * 8);
        *(uint4*)((char*)Es + swz512(row, cc * 16)) = v;
        const ushort* us = (const ushort*)&v;
        float s = 0.f;
#pragma unroll
        for (int j = 0; j < 8; ++j) s += bf2f(us[j]);
        part[p] = s;
    }
    rowssL[t >> 2][t & 3] = 0.f;
#pragma unroll
    for (int p = 0; p < 8; ++p) {
        float s = part[p];
        s += __shfl_xor(s, 1);  s += __shfl_xor(s, 2);
        s += __shfl_xor(s, 4);  s += __shfl_xor(s, 8);
        s += __shfl_xor(s, 16);
        if ((l & 31) == 0) rsumL[rr + p * 16] = s;
    }

    // ---- prefetch ctx_tiled tile dt=0 ----
    const ushort* Cb = ctxt + (size_t)b * 2 * 16 * 8192;
    const int sr = t >> 4, c4 = (t & 15) * 4;
    auto csrc = [&](int dt, int p) {
        int S = p * 32 + sr;
        int sh2 = S >> 7, r2 = S & 127;
        int kt = dh * 8 + dt;
        return Cb + (size_t)(sh2 * 16 + kt) * 8192 + r2 * 64 + c4;
    };
    uint2 cr[8];
#pragma unroll
    for (int p = 0; p < 8; ++p) cr[p] = *(const uint2*)csrc(0, p);

    __syncthreads();
    if (t < 128) rinv[t] = 1.0f / rsumL[t];

#pragma unroll
    for (int p = 0; p < 8; ++p) {
        int s = p * 32 + sr;
        const ushort* us = (const ushort*)&cr[p];
        Bs[(c4 + 0) * 264 + s] = us[0];
        Bs[(c4 + 1) * 264 + s] = us[1];
        Bs[(c4 + 2) * 264 + s] = us[2];
        Bs[(c4 + 3) * 264 + s] = us[3];
    }
    __syncthreads();

    ushort* Ob = wctx + (size_t)b * LQ * D + dglob0;

#pragma unroll 1
    for (int dt = 0; dt < 8; ++dt) {
        if (dt < 7) {
#pragma unroll
            for (int p = 0; p < 8; ++p) cr[p] = *(const uint2*)csrc(dt + 1, p);
        }
        f32x4 acc[4] = {};
#pragma unroll
        for (int kk = 0; kk < 8; ++kk) {
            const ushort* bp = Bs + (wd * 16 + (l & 15)) * 264 + kk * 32 + (l >> 4) * 8;
            bf16x8 bfr = *(const bf16x8*)bp;
#pragma unroll
            for (int i = 0; i < 4; ++i) {
                bf16x8 af = *(const bf16x8*)((const char*)Es +
                    swz512(wq * 64 + i * 16 + (l & 15), kk * 64 + (l >> 4) * 16));
                acc[i] = mfma16(af, bfr, acc[i]);
            }
        }
#pragma unroll
        for (int i = 0; i < 4; ++i)
#pragma unroll
            for (int r = 0; r < 4; ++r) {
                int row = wq * 64 + i * 16 + (l >> 4) * 4 + r;
                float wval = acc[i][r] * rinv[row];
                float p2 = wval * wval;
                p2 += __shfl_xor(p2, 1); p2 += __shfl_xor(p2, 2);
                p2 += __shfl_xor(p2, 4); p2 += __shfl_xor(p2, 8);
                if ((l & 15) == 0) rowssL[row][wd] += p2;
                Ob[(size_t)row * D + dt * 64 + wd * 16 + (l & 15)] = f2bf(wval);
            }
        __syncthreads();
        if (dt < 7) {
#pragma unroll
            for (int p = 0; p < 8; ++p) {
                int s = p * 32 + sr;
                const ushort* us = (const ushort*)&cr[p];
                Bs[(c4 + 0) * 264 + s] = us[0];
                Bs[(c4 + 1) * 264 + s] = us[1];
                Bs[(c4 + 2) * 264 + s] = us[2];
                Bs[(c4 + 3) * 264 + s] = us[3];
            }
            __syncthreads();
        }
    }
    if (t < 128)
        rowssP[(size_t)b * 256 + dh * 128 + t] =
            rowssL[t][0] + rowssL[t][1] + rowssL[t][2] + rowssL[t][3];
}

// =====================================================================
// gemm3+finalnorm: out[b][q][k] = l2norm_k( sum_d sr[q][d]*Wb[k][d] + b[k] )
// sr on the fly: (query - wctx*invq)^2 with invq from rowssP halves.
// BM=64(q) BN=256 BK=64. 512 thr, 8 waves 2x4.
// =====================================================================
__global__ __launch_bounds__(512, 2) void gemm3_kernel(
    const ushort* __restrict__ wctx, const float* __restrict__ query,
    const float* __restrict__ rowssP, const ushort* __restrict__ Wb,
    const float* __restrict__ bias, float* __restrict__ out)
{
    const int m0 = blockIdx.x * 64;
    const int b  = blockIdx.y;
    __shared__ ushort As[64 * 64];
    __shared__ ushort Bs[256 * 64];
    __shared__ float red[64][4];
    __shared__ float invr[64];
    const int t = threadIdx.x;
    const int w = t >> 6, l = t & 63;
    const int wm = (w >> 2) * 32, wn = (w & 3) * 64;

    const int arow = t >> 3, ako = (t & 7) * 8;
    const float r0v = rowssP[(size_t)b * 256 + m0 + arow];
    const float r1v = rowssP[(size_t)b * 256 + 128 + m0 + arow];
    const float ivq = 1.0f / (sqrtf(r0v + r1v) + EPS);
    const float* Qp  = query + ((size_t)b * LQ + m0 + arow) * D + ako;
    const ushort* Wp = wctx  + ((size_t)b * LQ + m0 + arow) * D + ako;

    f32x4 acc[2][4] = {};

    for (int k0 = 0; k0 < D; k0 += 64) {
        if (k0) __syncthreads();
        {   // A: sr on the fly
            uint4 wu = *(const uint4*)(Wp + k0);
            float4 q1 = *(const float4*)(Qp + k0);
            float4 q2 = *(const float4*)(Qp + k0 + 4);
            float d0 = q1.x - bf2f((ushort)(wu.x & 0xffff)) * ivq;
            float d1 = q1.y - bf2f((ushort)(wu.x >> 16))    * ivq;
            float d2 = q1.z - bf2f((ushort)(wu.y & 0xffff)) * ivq;
            float d3 = q1.w - bf2f((ushort)(wu.y >> 16))    * ivq;
            float d4 = q2.x - bf2f((ushort)(wu.z & 0xffff)) * ivq;
            float d5 = q2.y - bf2f((ushort)(wu.z >> 16))    * ivq;
            float d6 = q2.z - bf2f((ushort)(wu.w & 0xffff)) * ivq;
            float d7 = q2.w - bf2f((ushort)(wu.w >> 16))    * ivq;
            float4 s1{d0*d0, d1*d1, d2*d2, d3*d3};
            float4 s2{d4*d4, d5*d5, d6*d6, d7*d7};
            *(uint4*)((char*)As + swz(arow, ako * 2)) = pack8(s1, s2);
        }
#pragma unroll
        for (int j = 0; j < 4; ++j) {   // B: Wb
            int c = t + j * 512;
            int row = c >> 3, ko = (c & 7) * 8;
            *(uint4*)((char*)Bs + swz(row, ko * 2)) =
                *(const uint4*)(Wb + (size_t)row * D + k0 + ko);
        }
        __syncthreads();
#pragma unroll
        for (int kk = 0; kk < 2; ++kk) {
            bf16x8 af[2], bfr[4];
#pragma unroll
            for (int i = 0; i < 2; ++i) af[i] = lds_frag(As, wm + i * 16 + (l & 15), kk, l);
#pragma unroll
            for (int n = 0; n < 4; ++n) bfr[n] = lds_frag(Bs, wn + n * 16 + (l & 15), kk, l);
#pragma unroll
            for (int i = 0; i < 2; ++i)
#pragma unroll
                for (int n = 0; n < 4; ++n) acc[i][n] = mfma16(af[i], bfr[n], acc[i][n]);
        }
    }
#pragma unroll
    for (int n = 0; n < 4; ++n) {
        float bv = bias[wn + n * 16 + (l & 15)];
#pragma unroll
        for (int i = 0; i < 2; ++i)
#pragma unroll
            for (int r = 0; r < 4; ++r) acc[i][n][r] += bv;
    }
#pragma unroll
    for (int i = 0; i < 2; ++i)
#pragma unroll
        for (int r = 0; r < 4; ++r) {
            float p = 0.f;
#pragma unroll
            for (int n = 0; n < 4; ++n) p += acc[i][n][r] * acc[i][n][r];
#pragma unroll
            for (int off = 1; off < 16; off <<= 1) p += __shfl_xor(p, off);
            int rowl = wm + i * 16 + (l >> 4) * 4 + r;
            if ((l & 15) == 0) red[rowl][w & 3] = p;
        }
    __syncthreads();
    if (t < 64) {
        float s = red[t][0] + red[t][1] + red[t][2] + red[t][3];
        invr[t] = 1.0f / (sqrtf(s) + EPS);
    }
    __syncthreads();
    float* Ob = out + ((size_t)b * LQ + m0) * SD;
#pragma unroll
    for (int i = 0; i < 2; ++i)
#pragma unroll
        for (int r = 0; r < 4; ++r) {
            int rowl = wm + i * 16 + (l >> 4) * 4 + r;
            float iv = invr[rowl];
#pragma unroll
            for (int n = 0; n < 4; ++n) {
                int col = wn + n * 16 + (l & 15);
                Ob[(size_t)rowl * SD + col] = acc[i][n][r] * iv;
            }
        }
}

// =====================================================================
extern "C" void kernel_launch(void* const* d_in, const int* in_sizes, int n_in,
                              void* d_out, int out_size, void* d_ws, size_t ws_size,
                              hipStream_t stream)
{
    const float* query  = (const float*)d_in[0];
    const float* ctx    = (const float*)d_in[1];
    const float* mat    = (const float*)d_in[2];
    const float* W      = (const float*)d_in[3];
    const float* bias   = (const float*)d_in[4];
    const int*   smooth = (const int*)d_in[5];
    float* out = (float*)d_out;

    char* ws = (char*)d_ws;
    ushort* ctxt   = (ushort*)ws;                                   // 64 MiB
    ushort* qmt    = (ushort*)(ws + (size_t)64 * 1024 * 1024);      // 32 MiB
    ushort* wctx   = qmt;   // overlay: qmt dead after gemmA, wctx written by pv
    ushort* E      = (ushort*)(ws + (size_t)96 * 1024 * 1024);      //  8 MiB
    ushort* Wb     = (ushort*)(ws + (size_t)104 * 1024 * 1024);     // 0.5 MiB
    float*  rowssP = (float*)(ws + (size_t)(104 * 1024 + 512) * 1024); // 128 KiB

    wconv_kernel<<<dim3(SD * D / (256 * 8)), 256, 0, stream>>>(W, Wb);
    qmpack_kernel<<<dim3((size_t)B * LQ * D / (256 * 8)), 256, 0, stream>>>(query, mat, qmt);
    cpack_kernel<<<dim3((size_t)B * LS * D / (256 * 8)), 256, 0, stream>>>(ctx, ctxt);
    gemmA_kernel<<<dim3(256), 512, 0, stream>>>(qmt, ctxt, smooth, E);
    pv_kernel<<<dim3(256), 512, 0, stream>>>(E, ctxt, wctx, rowssP);
    gemm3_kernel<<<dim3(2, B), 512, 0, stream>>>(wctx, query, rowssP, Wb, bias, out);
}

// Round 18
// 149.069 us; speedup vs baseline: 1.1872x; 1.1872x over previous
//
#include <hip/hip_runtime.h>
#include <hip/hip_bf16.h>

constexpr int B  = 128;
constexpr int LQ = 128;
constexpr int LS = 256;
constexpr int D  = 1024;
constexpr int SD = 256;
constexpr float EPS = 1e-8f;

typedef __attribute__((ext_vector_type(8))) __bf16 bf16x8;
typedef __attribute__((ext_vector_type(4))) float f32x4;

__device__ inline ushort f2bf(float f) {
    union { float f; uint u; } v{f};
    uint r = v.u + 0x7fffu + ((v.u >> 16) & 1u);   // RNE
    return (ushort)(r >> 16);
}
__device__ inline float bf2f(ushort u) {
    union { uint u; float f; } v{(uint)u << 16};
    return v.f;
}
__device__ inline uint4 pack8(float4 a, float4 b) {
    union { ushort us[8]; uint4 u4; } r;
    r.us[0]=f2bf(a.x); r.us[1]=f2bf(a.y); r.us[2]=f2bf(a.z); r.us[3]=f2bf(a.w);
    r.us[4]=f2bf(b.x); r.us[5]=f2bf(b.y); r.us[6]=f2bf(b.z); r.us[7]=f2bf(b.w);
    return r.u4;
}
// 128B-row LDS tiles (64 bf16): XOR-swizzle bank fix
__device__ inline int swz(int row, int kbyte) {
    return row * 128 + (kbyte ^ ((row & 7) << 4));
}
__device__ inline bf16x8 lds_frag(const ushort* base, int row, int kk, int lane) {
    int kbyte = kk * 64 + (lane >> 4) * 16;
    return *(const bf16x8*)((const char*)base + swz(row, kbyte));
}
// 512B-row LDS tiles (256 bf16): same XOR pattern
__device__ inline int swz512(int row, int kbyte) {
    return row * 512 + (kbyte ^ ((row & 7) << 4));
}
__device__ inline f32x4 mfma16(bf16x8 a, bf16x8 b, f32x4 c) {
    return __builtin_amdgcn_mfma_f32_16x16x32_bf16(a, b, c, 0, 0, 0);
}

// =====================================================================
// Wb (bf16) <- W fp32
// =====================================================================
__global__ __launch_bounds__(256) void wconv_kernel(
    const float* __restrict__ W, ushort* __restrict__ Wb)
{
    size_t i = ((size_t)blockIdx.x * 256 + threadIdx.x) * 8;
    float4 a = *(const float4*)(W + i);
    float4 b = *(const float4*)(W + i + 4);
    *(uint4*)(Wb + i) = pack8(a, b);
}

// =====================================================================
// gemmA: per block (b, s-half of 128):
//   A-stage: qm = query*matrix fp32 -> bf16 (fused)
//   S = leaky(qm . ctx^T); col-l2norm over q (all 128 in-block);
//   E = exp(S*inv*smooth) bf16 (LDS-gathered, coalesced store).
// Grid 256 = (b x 2 s-halves), XCD-swizzled. 512 thr, 8 waves 2q x 4s.
// BM=128 BN=128 BK=64, double-buffered LDS (64 KB).
// Best-measured configuration (r11, 149.8 us end-to-end).
// =====================================================================
__global__ __launch_bounds__(512, 2) void gemmA_kernel(
    const float* __restrict__ query, const float* __restrict__ mat,
    const float* __restrict__ ctx, const int* __restrict__ smooth_p,
    ushort* __restrict__ E)
{
    const int bid = blockIdx.x;            // 256 blocks
    const int xcd = bid & 7, idx = bid >> 3;
    const int b  = xcd * 16 + (idx >> 1);
    const int sh = idx & 1;
    const int n0 = sh * 128;               // s-offset
    __shared__ ushort SH[4][128 * 64];     // As0,As1,Bs0,Bs1 (64 KB)
    __shared__ float colssP[2][128];
    __shared__ float invsm[128];
    ushort* Et = &SH[0][0];                // epilogue alias: 128 x 136

    const int t = threadIdx.x;
    const int wv = t >> 6, l = t & 63;
    const int wq = wv >> 2, wsv = wv & 3;

    const float* Qb = query + (size_t)b * LQ * D;
    const float* Mb = mat   + (size_t)b * LQ * D;
    const float* Cb = ctx   + ((size_t)b * LS + n0) * D;
    const int r0 = t >> 3, k8 = (t & 7) * 8;

    f32x4 acc[4][2] = {};
    float4 q0,q1,q2,q3, m0,m1,m2,m3, c0,c1,c2,c3;

    auto loadT = [&](int k0) {
        const float* qp = Qb + (size_t)r0 * D + k0 + k8;
        const float* mp = Mb + (size_t)r0 * D + k0 + k8;
        q0 = *(const float4*)qp; q1 = *(const float4*)(qp + 4);
        m0 = *(const float4*)mp; m1 = *(const float4*)(mp + 4);
        qp += (size_t)64 * D;  mp += (size_t)64 * D;
        q2 = *(const float4*)qp; q3 = *(const float4*)(qp + 4);
        m2 = *(const float4*)mp; m3 = *(const float4*)(mp + 4);
        const float* cp = Cb + (size_t)r0 * D + k0 + k8;
        c0 = *(const float4*)cp; c1 = *(const float4*)(cp + 4);
        cp += (size_t)64 * D;
        c2 = *(const float4*)cp; c3 = *(const float4*)(cp + 4);
    };
    auto storeT = [&](int buf) {
        float4 p1{q0.x*m0.x, q0.y*m0.y, q0.z*m0.z, q0.w*m0.w};
        float4 p2{q1.x*m1.x, q1.y*m1.y, q1.z*m1.z, q1.w*m1.w};
        *(uint4*)((char*)&SH[buf][0] + swz(r0, k8 * 2)) = pack8(p1, p2);
        float4 p3{q2.x*m2.x, q2.y*m2.y, q2.z*m2.z, q2.w*m2.w};
        float4 p4{q3.x*m3.x, q3.y*m3.y, q3.z*m3.z, q3.w*m3.w};
        *(uint4*)((char*)&SH[buf][0] + swz(r0 + 64, k8 * 2)) = pack8(p3, p4);
        *(uint4*)((char*)&SH[2 + buf][0] + swz(r0, k8 * 2))      = pack8(c0, c1);
        *(uint4*)((char*)&SH[2 + buf][0] + swz(r0 + 64, k8 * 2)) = pack8(c2, c3);
    };
    auto mfmaT = [&](int buf) {
#pragma unroll
        for (int kk = 0; kk < 2; ++kk) {
            bf16x8 bfr0 = lds_frag(&SH[2 + buf][0], wsv * 32 + (l & 15), kk, l);
            bf16x8 bfr1 = lds_frag(&SH[2 + buf][0], wsv * 32 + 16 + (l & 15), kk, l);
#pragma unroll
            for (int i = 0; i < 4; ++i) {
                bf16x8 af = lds_frag(&SH[buf][0], wq * 64 + i * 16 + (l & 15), kk, l);
                acc[i][0] = mfma16(af, bfr0, acc[i][0]);
                acc[i][1] = mfma16(af, bfr1, acc[i][1]);
            }
        }
    };

    loadT(0);
    storeT(0);
    __syncthreads();
    int cur = 0;
#pragma unroll 1
    for (int ks = 0; ks < 15; ++ks) {
        loadT((ks + 1) * 64);
        mfmaT(cur);
        storeT(cur ^ 1);
        __syncthreads();
        cur ^= 1;
    }
    mfmaT(cur);

    // ---- epilogue: leaky + col sumsq -> invsm -> E = exp ----
#pragma unroll
    for (int n = 0; n < 2; ++n) {
        float csum = 0.f;
#pragma unroll
        for (int i = 0; i < 4; ++i)
#pragma unroll
            for (int r = 0; r < 4; ++r) {
                float v = acc[i][n][r];
                v = v >= 0.f ? v : 0.1f * v;
                acc[i][n][r] = v;
                csum += v * v;
            }
        csum += __shfl_xor(csum, 16);
        csum += __shfl_xor(csum, 32);
        if (l < 16) colssP[wq][wsv * 32 + n * 16 + l] = csum;
    }
    __syncthreads();   // all MFMA reads done -> SH reusable as Et
    const float sm = (float)(*smooth_p);
    if (t < 128) invsm[t] = sm / (sqrtf(colssP[0][t] + colssP[1][t]) + EPS);
    __syncthreads();
#pragma unroll
    for (int n = 0; n < 2; ++n) {
        const float invc = invsm[wsv * 32 + n * 16 + (l & 15)];
#pragma unroll
        for (int i = 0; i < 4; ++i)
#pragma unroll
            for (int r = 0; r < 4; ++r) {
                int row = wq * 64 + i * 16 + (l >> 4) * 4 + r;
                Et[row * 136 + wsv * 32 + n * 16 + (l & 15)] =
                    f2bf(__expf(acc[i][n][r] * invc));
            }
    }
    __syncthreads();
    // coalesced E store: 128 rows x 16 uint4 chunks = 2048, 4/thread
    ushort* Eg = E + (size_t)b * LQ * LS + n0;
#pragma unroll
    for (int j = 0; j < 4; ++j) {
        int c = t + j * 512;
        int row = c >> 4, s8 = (c & 15) * 8;
        *(uint4*)(Eg + (size_t)row * LS + s8) = *(const uint4*)(Et + row * 136 + s8);
    }
}

// =====================================================================
// pv: wctx[128q][512d-half] = (E . ctx^T) * (1/rowsum(E)); rowss partials.
// Grid 256 = (b x 2 dh), XCD-swizzled. 512 thr, 8 waves 2q x 4d.
// B staged DIRECTLY from fp32 ctx (L3-hot after gemmA) via in-LDS
// transpose into padded Bs[64][264]. Reg-prefetch per dt.
// =====================================================================
__global__ __launch_bounds__(512, 2) void pv_kernel(
    const ushort* __restrict__ E, const float* __restrict__ ctx,
    ushort* __restrict__ wctx, float* __restrict__ rowssP)
{
    const int bid = blockIdx.x;
    const int xcd = bid & 7, idx = bid >> 3;
    const int b  = xcd * 16 + (idx >> 1);
    const int dh = idx & 1;
    const int dglob0 = dh * 512;

    __shared__ ushort Es[128 * 256];       // 64 KB swz512
    __shared__ ushort Bs[64 * 264];        // 33 KB padded [d][s+8]
    __shared__ float rsumL[128];
    __shared__ float rinv[128];
    __shared__ float rowssL[128][4];

    const int t = threadIdx.x;
    const int wv = t >> 6, l = t & 63;
    const int wq = wv >> 2, wd = wv & 3;

    // ---- stage E (128q x 256s) + per-row exp sums ----
    const ushort* Eb = E + (size_t)b * LQ * LS;
    const int cc = t & 31, rr = t >> 5;
    float part[8];
#pragma unroll
    for (int p = 0; p < 8; ++p) {
        int row = rr + p * 16;
        uint4 v = *(const uint4*)(Eb + (size_t)row * LS + cc * 8);
        *(uint4*)((char*)Es + swz512(row, cc * 16)) = v;
        const ushort* us = (const ushort*)&v;
        float s = 0.f;
#pragma unroll
        for (int j = 0; j < 8; ++j) s += bf2f(us[j]);
        part[p] = s;
    }
    rowssL[t >> 2][t & 3] = 0.f;
#pragma unroll
    for (int p = 0; p < 8; ++p) {
        float s = part[p];
        s += __shfl_xor(s, 1);  s += __shfl_xor(s, 2);
        s += __shfl_xor(s, 4);  s += __shfl_xor(s, 8);
        s += __shfl_xor(s, 16);
        if ((l & 31) == 0) rsumL[rr + p * 16] = s;
    }

    // ---- prefetch ctx tile dt=0 (coalesced float4 rows) ----
    const float* Cb = ctx + (size_t)b * LS * D + dglob0;
    const int sr = t >> 4, c4 = (t & 15) * 4;
    float4 cr[8];
#pragma unroll
    for (int p = 0; p < 8; ++p)
        cr[p] = *(const float4*)(Cb + (size_t)(p * 32 + sr) * D + c4);

    __syncthreads();
    if (t < 128) rinv[t] = 1.0f / rsumL[t];

#pragma unroll
    for (int p = 0; p < 8; ++p) {
        int s = p * 32 + sr;
        Bs[(c4 + 0) * 264 + s] = f2bf(cr[p].x);
        Bs[(c4 + 1) * 264 + s] = f2bf(cr[p].y);
        Bs[(c4 + 2) * 264 + s] = f2bf(cr[p].z);
        Bs[(c4 + 3) * 264 + s] = f2bf(cr[p].w);
    }
    __syncthreads();

    ushort* Ob = wctx + (size_t)b * LQ * D + dglob0;

#pragma unroll 1
    for (int dt = 0; dt < 8; ++dt) {
        if (dt < 7) {
#pragma unroll
            for (int p = 0; p < 8; ++p)
                cr[p] = *(const float4*)(Cb + (size_t)(p * 32 + sr) * D + (dt + 1) * 64 + c4);
        }
        f32x4 acc[4] = {};
#pragma unroll
        for (int kk = 0; kk < 8; ++kk) {
            const ushort* bp = Bs + (wd * 16 + (l & 15)) * 264 + kk * 32 + (l >> 4) * 8;
            bf16x8 bfr = *(const bf16x8*)bp;
#pragma unroll
            for (int i = 0; i < 4; ++i) {
                bf16x8 af = *(const bf16x8*)((const char*)Es +
                    swz512(wq * 64 + i * 16 + (l & 15), kk * 64 + (l >> 4) * 16));
                acc[i] = mfma16(af, bfr, acc[i]);
            }
        }
#pragma unroll
        for (int i = 0; i < 4; ++i)
#pragma unroll
            for (int r = 0; r < 4; ++r) {
                int row = wq * 64 + i * 16 + (l >> 4) * 4 + r;
                float wval = acc[i][r] * rinv[row];
                float p2 = wval * wval;
                p2 += __shfl_xor(p2, 1); p2 += __shfl_xor(p2, 2);
                p2 += __shfl_xor(p2, 4); p2 += __shfl_xor(p2, 8);
                if ((l & 15) == 0) rowssL[row][wd] += p2;
                Ob[(size_t)row * D + dt * 64 + wd * 16 + (l & 15)] = f2bf(wval);
            }
        __syncthreads();
        if (dt < 7) {
#pragma unroll
            for (int p = 0; p < 8; ++p) {
                int s = p * 32 + sr;
                Bs[(c4 + 0) * 264 + s] = f2bf(cr[p].x);
                Bs[(c4 + 1) * 264 + s] = f2bf(cr[p].y);
                Bs[(c4 + 2) * 264 + s] = f2bf(cr[p].z);
                Bs[(c4 + 3) * 264 + s] = f2bf(cr[p].w);
            }
            __syncthreads();
        }
    }
    if (t < 128)
        rowssP[(size_t)b * 256 + dh * 128 + t] =
            rowssL[t][0] + rowssL[t][1] + rowssL[t][2] + rowssL[t][3];
}

// =====================================================================
// gemm3+finalnorm: out[b][q][k] = l2norm_k( sum_d sr[q][d]*Wb[k][d] + b[k] )
// sr on the fly: (query - wctx*invq)^2 with invq from rowssP halves.
// BM=64(q) BN=256 BK=64. 512 thr, 8 waves 2x4.
// =====================================================================
__global__ __launch_bounds__(512, 2) void gemm3_kernel(
    const ushort* __restrict__ wctx, const float* __restrict__ query,
    const float* __restrict__ rowssP, const ushort* __restrict__ Wb,
    const float* __restrict__ bias, float* __restrict__ out)
{
    const int m0 = blockIdx.x * 64;
    const int b  = blockIdx.y;
    __shared__ ushort As[64 * 64];
    __shared__ ushort Bs[256 * 64];
    __shared__ float red[64][4];
    __shared__ float invr[64];
    const int t = threadIdx.x;
    const int w = t >> 6, l = t & 63;
    const int wm = (w >> 2) * 32, wn = (w & 3) * 64;

    const int arow = t >> 3, ako = (t & 7) * 8;
    const float r0v = rowssP[(size_t)b * 256 + m0 + arow];
    const float r1v = rowssP[(size_t)b * 256 + 128 + m0 + arow];
    const float ivq = 1.0f / (sqrtf(r0v + r1v) + EPS);
    const float* Qp  = query + ((size_t)b * LQ + m0 + arow) * D + ako;
    const ushort* Wp = wctx  + ((size_t)b * LQ + m0 + arow) * D + ako;

    f32x4 acc[2][4] = {};

    for (int k0 = 0; k0 < D; k0 += 64) {
        if (k0) __syncthreads();
        {   // A: sr on the fly
            uint4 wu = *(const uint4*)(Wp + k0);
            float4 q1 = *(const float4*)(Qp + k0);
            float4 q2 = *(const float4*)(Qp + k0 + 4);
            float d0 = q1.x - bf2f((ushort)(wu.x & 0xffff)) * ivq;
            float d1 = q1.y - bf2f((ushort)(wu.x >> 16))    * ivq;
            float d2 = q1.z - bf2f((ushort)(wu.y & 0xffff)) * ivq;
            float d3 = q1.w - bf2f((ushort)(wu.y >> 16))    * ivq;
            float d4 = q2.x - bf2f((ushort)(wu.z & 0xffff)) * ivq;
            float d5 = q2.y - bf2f((ushort)(wu.z >> 16))    * ivq;
            float d6 = q2.z - bf2f((ushort)(wu.w & 0xffff)) * ivq;
            float d7 = q2.w - bf2f((ushort)(wu.w >> 16))    * ivq;
            float4 s1{d0*d0, d1*d1, d2*d2, d3*d3};
            float4 s2{d4*d4, d5*d5, d6*d6, d7*d7};
            *(uint4*)((char*)As + swz(arow, ako * 2)) = pack8(s1, s2);
        }
#pragma unroll
        for (int j = 0; j < 4; ++j) {   // B: Wb
            int c = t + j * 512;
            int row = c >> 3, ko = (c & 7) * 8;
            *(uint4*)((char*)Bs + swz(row, ko * 2)) =
                *(const uint4*)(Wb + (size_t)row * D + k0 + ko);
        }
        __syncthreads();
#pragma unroll
        for (int kk = 0; kk < 2; ++kk) {
            bf16x8 af[2], bfr[4];
#pragma unroll
            for (int i = 0; i < 2; ++i) af[i] = lds_frag(As, wm + i * 16 + (l & 15), kk, l);
#pragma unroll
            for (int n = 0; n < 4; ++n) bfr[n] = lds_frag(Bs, wn + n * 16 + (l & 15), kk, l);
#pragma unroll
            for (int i = 0; i < 2; ++i)
#pragma unroll
                for (int n = 0; n < 4; ++n) acc[i][n] = mfma16(af[i], bfr[n], acc[i][n]);
        }
    }
#pragma unroll
    for (int n = 0; n < 4; ++n) {
        float bv = bias[wn + n * 16 + (l & 15)];
#pragma unroll
        for (int i = 0; i < 2; ++i)
#pragma unroll
            for (int r = 0; r < 4; ++r) acc[i][n][r] += bv;
    }
#pragma unroll
    for (int i = 0; i < 2; ++i)
#pragma unroll
        for (int r = 0; r < 4; ++r) {
            float p = 0.f;
#pragma unroll
            for (int n = 0; n < 4; ++n) p += acc[i][n][r] * acc[i][n][r];
#pragma unroll
            for (int off = 1; off < 16; off <<= 1) p += __shfl_xor(p, off);
            int rowl = wm + i * 16 + (l >> 4) * 4 + r;
            if ((l & 15) == 0) red[rowl][w & 3] = p;
        }
    __syncthreads();
    if (t < 64) {
        float s = red[t][0] + red[t][1] + red[t][2] + red[t][3];
        invr[t] = 1.0f / (sqrtf(s) + EPS);
    }
    __syncthreads();
    float* Ob = out + ((size_t)b * LQ + m0) * SD;
#pragma unroll
    for (int i = 0; i < 2; ++i)
#pragma unroll
        for (int r = 0; r < 4; ++r) {
            int rowl = wm + i * 16 + (l >> 4) * 4 + r;
            float iv = invr[rowl];
#pragma unroll
            for (int n = 0; n < 4; ++n) {
                int col = wn + n * 16 + (l & 15);
                Ob[(size_t)rowl * SD + col] = acc[i][n][r] * iv;
            }
        }
}

// =====================================================================
extern "C" void kernel_launch(void* const* d_in, const int* in_sizes, int n_in,
                              void* d_out, int out_size, void* d_ws, size_t ws_size,
                              hipStream_t stream)
{
    const float* query  = (const float*)d_in[0];
    const float* ctx    = (const float*)d_in[1];
    const float* mat    = (const float*)d_in[2];
    const float* W      = (const float*)d_in[3];
    const float* bias   = (const float*)d_in[4];
    const int*   smooth = (const int*)d_in[5];
    float* out = (float*)d_out;

    char* ws = (char*)d_ws;
    ushort* wctx   = (ushort*)ws;                                   // 32 MiB
    ushort* E      = (ushort*)(ws + (size_t)32 * 1024 * 1024);      //  8 MiB
    ushort* Wb     = (ushort*)(ws + (size_t)40 * 1024 * 1024);      // 0.5 MiB
    float*  rowssP = (float*)(ws + (size_t)(40 * 1024 + 512) * 1024); // 128 KiB

    wconv_kernel<<<dim3(SD * D / (256 * 8)), 256, 0, stream>>>(W, Wb);
    gemmA_kernel<<<dim3(256), 512, 0, stream>>>(query, mat, ctx, smooth, E);
    pv_kernel<<<dim3(256), 512, 0, stream>>>(E, ctx, wctx, rowssP);
    gemm3_kernel<<<dim3(2, B), 512, 0, stream>>>(wctx, query, rowssP, Wb, bias, out);
}

// Round 19
// 147.067 us; speedup vs baseline: 1.2034x; 1.0136x over previous
//
#include <hip/hip_runtime.h>
#include <hip/hip_bf16.h>

constexpr int B  = 128;
constexpr int LQ = 128;
constexpr int LS = 256;
constexpr int D  = 1024;
constexpr int SD = 256;
constexpr float EPS = 1e-8f;

typedef __attribute__((ext_vector_type(8))) __bf16 bf16x8;
typedef __attribute__((ext_vector_type(4))) float f32x4;

__device__ inline ushort f2bf(float f) {
    union { float f; uint u; } v{f};
    uint r = v.u + 0x7fffu + ((v.u >> 16) & 1u);   // RNE
    return (ushort)(r >> 16);
}
__device__ inline float bf2f(ushort u) {
    union { uint u; float f; } v{(uint)u << 16};
    return v.f;
}
__device__ inline uint4 pack8(float4 a, float4 b) {
    union { ushort us[8]; uint4 u4; } r;
    r.us[0]=f2bf(a.x); r.us[1]=f2bf(a.y); r.us[2]=f2bf(a.z); r.us[3]=f2bf(a.w);
    r.us[4]=f2bf(b.x); r.us[5]=f2bf(b.y); r.us[6]=f2bf(b.z); r.us[7]=f2bf(b.w);
    return r.u4;
}
// 128B-row LDS tiles (64 bf16): XOR-swizzle bank fix
__device__ inline int swz(int row, int kbyte) {
    return row * 128 + (kbyte ^ ((row & 7) << 4));
}
__device__ inline bf16x8 lds_frag(const ushort* base, int row, int kk, int lane) {
    int kbyte = kk * 64 + (lane >> 4) * 16;
    return *(const bf16x8*)((const char*)base + swz(row, kbyte));
}
// 512B-row LDS tiles (256 bf16): same XOR pattern
__device__ inline int swz512(int row, int kbyte) {
    return row * 512 + (kbyte ^ ((row & 7) << 4));
}
__device__ inline f32x4 mfma16(bf16x8 a, bf16x8 b, f32x4 c) {
    return __builtin_amdgcn_mfma_f32_16x16x32_bf16(a, b, c, 0, 0, 0);
}
// raw barrier: LDS-visibility wait only — global loads STAY IN FLIGHT
// (T4: __syncthreads would force s_waitcnt vmcnt(0), draining the pipeline)
__device__ inline void bar_lds() {
    asm volatile("s_waitcnt lgkmcnt(0)" ::: "memory");
    __builtin_amdgcn_s_barrier();
}

// =====================================================================
// Wb (bf16) <- W fp32
// =====================================================================
__global__ __launch_bounds__(256) void wconv_kernel(
    const float* __restrict__ W, ushort* __restrict__ Wb)
{
    size_t i = ((size_t)blockIdx.x * 256 + threadIdx.x) * 8;
    float4 a = *(const float4*)(W + i);
    float4 b = *(const float4*)(W + i + 4);
    *(uint4*)(Wb + i) = pack8(a, b);
}

// =====================================================================
// gemmA: per block (b, s-half of 128):
//   A-stage: qm = query*matrix fp32 -> bf16 (fused)
//   S = leaky(qm . ctx^T); col-l2norm over q; E = exp(S*inv*sm) bf16.
// Grid 256 = (b x 2 s-halves), XCD-swizzled. 512 thr, 8 waves 2q x 4s.
// BM=128 BN=128 BK=64, double-buffered LDS (64 KB).
// r19: DEPTH-2 REGISTER PIPELINE + RAW BARRIERS (T3/T4). Two named
// tile-sets rA/rB; tile k+2's loads issue BEFORE consuming tile k+1's
// regs -> compiler emits counted vmcnt (12 outstanding), and bar_lds()
// does not drain vmcnt. Every prior variant drained all loads at each
// K-step barrier (the 6x-refutation-surviving invariant).
// =====================================================================
struct TR { float4 q0,q1,q2,q3, m0,m1,m2,m3, c0,c1,c2,c3; };

__global__ __launch_bounds__(512, 2) void gemmA_kernel(
    const float* __restrict__ query, const float* __restrict__ mat,
    const float* __restrict__ ctx, const int* __restrict__ smooth_p,
    ushort* __restrict__ E)
{
    const int bid = blockIdx.x;            // 256 blocks
    const int xcd = bid & 7, idx = bid >> 3;
    const int b  = xcd * 16 + (idx >> 1);
    const int sh = idx & 1;
    const int n0 = sh * 128;               // s-offset
    __shared__ ushort SH[4][128 * 64];     // As0,As1,Bs0,Bs1 (64 KB)
    __shared__ float colssP[2][128];
    __shared__ float invsm[128];
    ushort* Et = &SH[0][0];                // epilogue alias: 128 x 136

    const int t = threadIdx.x;
    const int wv = t >> 6, l = t & 63;
    const int wq = wv >> 2, wsv = wv & 3;

    const float* Qb = query + (size_t)b * LQ * D;
    const float* Mb = mat   + (size_t)b * LQ * D;
    const float* Cb = ctx   + ((size_t)b * LS + n0) * D;
    const int r0 = t >> 3, k8 = (t & 7) * 8;

    f32x4 acc[4][2] = {};

    auto loadT = [&](TR& r, int k0) {
        const float* qp = Qb + (size_t)r0 * D + k0 + k8;
        const float* mp = Mb + (size_t)r0 * D + k0 + k8;
        r.q0 = *(const float4*)qp; r.q1 = *(const float4*)(qp + 4);
        r.m0 = *(const float4*)mp; r.m1 = *(const float4*)(mp + 4);
        qp += (size_t)64 * D;  mp += (size_t)64 * D;
        r.q2 = *(const float4*)qp; r.q3 = *(const float4*)(qp + 4);
        r.m2 = *(const float4*)mp; r.m3 = *(const float4*)(mp + 4);
        const float* cp = Cb + (size_t)r0 * D + k0 + k8;
        r.c0 = *(const float4*)cp; r.c1 = *(const float4*)(cp + 4);
        cp += (size_t)64 * D;
        r.c2 = *(const float4*)cp; r.c3 = *(const float4*)(cp + 4);
    };
    auto storeT = [&](const TR& r, int buf) {
        float4 p1{r.q0.x*r.m0.x, r.q0.y*r.m0.y, r.q0.z*r.m0.z, r.q0.w*r.m0.w};
        float4 p2{r.q1.x*r.m1.x, r.q1.y*r.m1.y, r.q1.z*r.m1.z, r.q1.w*r.m1.w};
        *(uint4*)((char*)&SH[buf][0] + swz(r0, k8 * 2)) = pack8(p1, p2);
        float4 p3{r.q2.x*r.m2.x, r.q2.y*r.m2.y, r.q2.z*r.m2.z, r.q2.w*r.m2.w};
        float4 p4{r.q3.x*r.m3.x, r.q3.y*r.m3.y, r.q3.z*r.m3.z, r.q3.w*r.m3.w};
        *(uint4*)((char*)&SH[buf][0] + swz(r0 + 64, k8 * 2)) = pack8(p3, p4);
        *(uint4*)((char*)&SH[2 + buf][0] + swz(r0, k8 * 2))      = pack8(r.c0, r.c1);
        *(uint4*)((char*)&SH[2 + buf][0] + swz(r0 + 64, k8 * 2)) = pack8(r.c2, r.c3);
    };
    auto mfmaT = [&](int buf) {
#pragma unroll
        for (int kk = 0; kk < 2; ++kk) {
            bf16x8 bfr0 = lds_frag(&SH[2 + buf][0], wsv * 32 + (l & 15), kk, l);
            bf16x8 bfr1 = lds_frag(&SH[2 + buf][0], wsv * 32 + 16 + (l & 15), kk, l);
#pragma unroll
            for (int i = 0; i < 4; ++i) {
                bf16x8 af = lds_frag(&SH[buf][0], wq * 64 + i * 16 + (l & 15), kk, l);
                acc[i][0] = mfma16(af, bfr0, acc[i][0]);
                acc[i][1] = mfma16(af, bfr1, acc[i][1]);
            }
        }
    };

    TR rA, rB;
    // prologue: tile0 staged; tile1 loads in flight across the barrier
    loadT(rA, 0);
    storeT(rA, 0);
    loadT(rB, 64);
    bar_lds();

    // main: 7 double-steps; even tiles in buf0, odd in buf1.
    // loads for tile k+2 issue BEFORE storeT consumes tile k+1's regs.
#pragma unroll 1
    for (int i = 0; i < 7; ++i) {
        const int k = i * 128;
        mfmaT(0);                    // tile 2i
        loadT(rA, k + 128);          // tile 2i+2 (in flight)
        storeT(rB, 1);               // tile 2i+1 (vmcnt counted, not 0)
        bar_lds();
        mfmaT(1);                    // tile 2i+1
        loadT(rB, k + 192);          // tile 2i+3 (in flight)
        storeT(rA, 0);               // tile 2i+2
        bar_lds();
    }
    mfmaT(0);                        // tile 14
    storeT(rB, 1);                   // tile 15
    bar_lds();
    mfmaT(1);                        // tile 15

    // ---- epilogue: leaky + col sumsq -> invsm -> E = exp ----
#pragma unroll
    for (int n = 0; n < 2; ++n) {
        float csum = 0.f;
#pragma unroll
        for (int i = 0; i < 4; ++i)
#pragma unroll
            for (int r = 0; r < 4; ++r) {
                float v = acc[i][n][r];
                v = v >= 0.f ? v : 0.1f * v;
                acc[i][n][r] = v;
                csum += v * v;
            }
        csum += __shfl_xor(csum, 16);
        csum += __shfl_xor(csum, 32);
        if (l < 16) colssP[wq][wsv * 32 + n * 16 + l] = csum;
    }
    __syncthreads();   // all MFMA reads done -> SH reusable as Et
    const float sm = (float)(*smooth_p);
    if (t < 128) invsm[t] = sm / (sqrtf(colssP[0][t] + colssP[1][t]) + EPS);
    __syncthreads();
#pragma unroll
    for (int n = 0; n < 2; ++n) {
        const float invc = invsm[wsv * 32 + n * 16 + (l & 15)];
#pragma unroll
        for (int i = 0; i < 4; ++i)
#pragma unroll
            for (int r = 0; r < 4; ++r) {
                int row = wq * 64 + i * 16 + (l >> 4) * 4 + r;
                Et[row * 136 + wsv * 32 + n * 16 + (l & 15)] =
                    f2bf(__expf(acc[i][n][r] * invc));
            }
    }
    __syncthreads();
    // coalesced E store: 128 rows x 16 uint4 chunks = 2048, 4/thread
    ushort* Eg = E + (size_t)b * LQ * LS + n0;
#pragma unroll
    for (int j = 0; j < 4; ++j) {
        int c = t + j * 512;
        int row = c >> 4, s8 = (c & 15) * 8;
        *(uint4*)(Eg + (size_t)row * LS + s8) = *(const uint4*)(Et + row * 136 + s8);
    }
}

// =====================================================================
// pv: wctx[128q][512d-half] = (E . ctx^T) * (1/rowsum(E)); rowss partials.
// Grid 256 = (b x 2 dh), XCD-swizzled. 512 thr, 8 waves 2q x 4d.
// B staged DIRECTLY from fp32 ctx via in-LDS transpose into padded
// Bs[64][264]. Reg-prefetch per dt.
// =====================================================================
__global__ __launch_bounds__(512, 2) void pv_kernel(
    const ushort* __restrict__ E, const float* __restrict__ ctx,
    ushort* __restrict__ wctx, float* __restrict__ rowssP)
{
    const int bid = blockIdx.x;
    const int xcd = bid & 7, idx = bid >> 3;
    const int b  = xcd * 16 + (idx >> 1);
    const int dh = idx & 1;
    const int dglob0 = dh * 512;

    __shared__ ushort Es[128 * 256];       // 64 KB swz512
    __shared__ ushort Bs[64 * 264];        // 33 KB padded [d][s+8]
    __shared__ float rsumL[128];
    __shared__ float rinv[128];
    __shared__ float rowssL[128][4];

    const int t = threadIdx.x;
    const int wv = t >> 6, l = t & 63;
    const int wq = wv >> 2, wd = wv & 3;

    // ---- stage E (128q x 256s) + per-row exp sums ----
    const ushort* Eb = E + (size_t)b * LQ * LS;
    const int cc = t & 31, rr = t >> 5;
    float part[8];
#pragma unroll
    for (int p = 0; p < 8; ++p) {
        int row = rr + p * 16;
        uint4 v = *(const uint4*)(Eb + (size_t)row * LS + cc * 8);
        *(uint4*)((char*)Es + swz512(row, cc * 16)) = v;
        const ushort* us = (const ushort*)&v;
        float s = 0.f;
#pragma unroll
        for (int j = 0; j < 8; ++j) s += bf2f(us[j]);
        part[p] = s;
    }
    rowssL[t >> 2][t & 3] = 0.f;
#pragma unroll
    for (int p = 0; p < 8; ++p) {
        float s = part[p];
        s += __shfl_xor(s, 1);  s += __shfl_xor(s, 2);
        s += __shfl_xor(s, 4);  s += __shfl_xor(s, 8);
        s += __shfl_xor(s, 16);
        if ((l & 31) == 0) rsumL[rr + p * 16] = s;
    }

    // ---- prefetch ctx tile dt=0 (coalesced float4 rows) ----
    const float* Cb = ctx + (size_t)b * LS * D + dglob0;
    const int sr = t >> 4, c4 = (t & 15) * 4;
    float4 cr[8];
#pragma unroll
    for (int p = 0; p < 8; ++p)
        cr[p] = *(const float4*)(Cb + (size_t)(p * 32 + sr) * D + c4);

    __syncthreads();
    if (t < 128) rinv[t] = 1.0f / rsumL[t];

#pragma unroll
    for (int p = 0; p < 8; ++p) {
        int s = p * 32 + sr;
        Bs[(c4 + 0) * 264 + s] = f2bf(cr[p].x);
        Bs[(c4 + 1) * 264 + s] = f2bf(cr[p].y);
        Bs[(c4 + 2) * 264 + s] = f2bf(cr[p].z);
        Bs[(c4 + 3) * 264 + s] = f2bf(cr[p].w);
    }
    __syncthreads();

    ushort* Ob = wctx + (size_t)b * LQ * D + dglob0;

#pragma unroll 1
    for (int dt = 0; dt < 8; ++dt) {
        if (dt < 7) {
#pragma unroll
            for (int p = 0; p < 8; ++p)
                cr[p] = *(const float4*)(Cb + (size_t)(p * 32 + sr) * D + (dt + 1) * 64 + c4);
        }
        f32x4 acc[4] = {};
#pragma unroll
        for (int kk = 0; kk < 8; ++kk) {
            const ushort* bp = Bs + (wd * 16 + (l & 15)) * 264 + kk * 32 + (l >> 4) * 8;
            bf16x8 bfr = *(const bf16x8*)bp;
#pragma unroll
            for (int i = 0; i < 4; ++i) {
                bf16x8 af = *(const bf16x8*)((const char*)Es +
                    swz512(wq * 64 + i * 16 + (l & 15), kk * 64 + (l >> 4) * 16));
                acc[i] = mfma16(af, bfr, acc[i]);
            }
        }
#pragma unroll
        for (int i = 0; i < 4; ++i)
#pragma unroll
            for (int r = 0; r < 4; ++r) {
                int row = wq * 64 + i * 16 + (l >> 4) * 4 + r;
                float wval = acc[i][r] * rinv[row];
                float p2 = wval * wval;
                p2 += __shfl_xor(p2, 1); p2 += __shfl_xor(p2, 2);
                p2 += __shfl_xor(p2, 4); p2 += __shfl_xor(p2, 8);
                if ((l & 15) == 0) rowssL[row][wd] += p2;
                Ob[(size_t)row * D + dt * 64 + wd * 16 + (l & 15)] = f2bf(wval);
            }
        __syncthreads();
        if (dt < 7) {
#pragma unroll
            for (int p = 0; p < 8; ++p) {
                int s = p * 32 + sr;
                Bs[(c4 + 0) * 264 + s] = f2bf(cr[p].x);
                Bs[(c4 + 1) * 264 + s] = f2bf(cr[p].y);
                Bs[(c4 + 2) * 264 + s] = f2bf(cr[p].z);
                Bs[(c4 + 3) * 264 + s] = f2bf(cr[p].w);
            }
            __syncthreads();
        }
    }
    if (t < 128)
        rowssP[(size_t)b * 256 + dh * 128 + t] =
            rowssL[t][0] + rowssL[t][1] + rowssL[t][2] + rowssL[t][3];
}

// =====================================================================
// gemm3+finalnorm: out[b][q][k] = l2norm_k( sum_d sr[q][d]*Wb[k][d] + b[k] )
// sr on the fly: (query - wctx*invq)^2 with invq from rowssP halves.
// BM=64(q) BN=256 BK=64. 512 thr, 8 waves 2x4.
// =====================================================================
__global__ __launch_bounds__(512, 2) void gemm3_kernel(
    const ushort* __restrict__ wctx, const float* __restrict__ query,
    const float* __restrict__ rowssP, const ushort* __restrict__ Wb,
    const float* __restrict__ bias, float* __restrict__ out)
{
    const int m0 = blockIdx.x * 64;
    const int b  = blockIdx.y;
    __shared__ ushort As[64 * 64];
    __shared__ ushort Bs[256 * 64];
    __shared__ float red[64][4];
    __shared__ float invr[64];
    const int t = threadIdx.x;
    const int w = t >> 6, l = t & 63;
    const int wm = (w >> 2) * 32, wn = (w & 3) * 64;

    const int arow = t >> 3, ako = (t & 7) * 8;
    const float r0v = rowssP[(size_t)b * 256 + m0 + arow];
    const float r1v = rowssP[(size_t)b * 256 + 128 + m0 + arow];
    const float ivq = 1.0f / (sqrtf(r0v + r1v) + EPS);
    const float* Qp  = query + ((size_t)b * LQ + m0 + arow) * D + ako;
    const ushort* Wp = wctx  + ((size_t)b * LQ + m0 + arow) * D + ako;

    f32x4 acc[2][4] = {};

    for (int k0 = 0; k0 < D; k0 += 64) {
        if (k0) __syncthreads();
        {   // A: sr on the fly
            uint4 wu = *(const uint4*)(Wp + k0);
            float4 q1 = *(const float4*)(Qp + k0);
            float4 q2 = *(const float4*)(Qp + k0 + 4);
            float d0 = q1.x - bf2f((ushort)(wu.x & 0xffff)) * ivq;
            float d1 = q1.y - bf2f((ushort)(wu.x >> 16))    * ivq;
            float d2 = q1.z - bf2f((ushort)(wu.y & 0xffff)) * ivq;
            float d3 = q1.w - bf2f((ushort)(wu.y >> 16))    * ivq;
            float d4 = q2.x - bf2f((ushort)(wu.z & 0xffff)) * ivq;
            float d5 = q2.y - bf2f((ushort)(wu.z >> 16))    * ivq;
            float d6 = q2.z - bf2f((ushort)(wu.w & 0xffff)) * ivq;
            float d7 = q2.w - bf2f((ushort)(wu.w >> 16))    * ivq;
            float4 s1{d0*d0, d1*d1, d2*d2, d3*d3};
            float4 s2{d4*d4, d5*d5, d6*d6, d7*d7};
            *(uint4*)((char*)As + swz(arow, ako * 2)) = pack8(s1, s2);
        }
#pragma unroll
        for (int j = 0; j < 4; ++j) {   // B: Wb
            int c = t + j * 512;
            int row = c >> 3, ko = (c & 7) * 8;
            *(uint4*)((char*)Bs + swz(row, ko * 2)) =
                *(const uint4*)(Wb + (size_t)row * D + k0 + ko);
        }
        __syncthreads();
#pragma unroll
        for (int kk = 0; kk < 2; ++kk) {
            bf16x8 af[2], bfr[4];
#pragma unroll
            for (int i = 0; i < 2; ++i) af[i] = lds_frag(As, wm + i * 16 + (l & 15), kk, l);
#pragma unroll
            for (int n = 0; n < 4; ++n) bfr[n] = lds_frag(Bs, wn + n * 16 + (l & 15), kk, l);
#pragma unroll
            for (int i = 0; i < 2; ++i)
#pragma unroll
                for (int n = 0; n < 4; ++n) acc[i][n] = mfma16(af[i], bfr[n], acc[i][n]);
        }
    }
#pragma unroll
    for (int n = 0; n < 4; ++n) {
        float bv = bias[wn + n * 16 + (l & 15)];
#pragma unroll
        for (int i = 0; i < 2; ++i)
#pragma unroll
            for (int r = 0; r < 4; ++r) acc[i][n][r] += bv;
    }
#pragma unroll
    for (int i = 0; i < 2; ++i)
#pragma unroll
        for (int r = 0; r < 4; ++r) {
            float p = 0.f;
#pragma unroll
            for (int n = 0; n < 4; ++n) p += acc[i][n][r] * acc[i][n][r];
#pragma unroll
            for (int off = 1; off < 16; off <<= 1) p += __shfl_xor(p, off);
            int rowl = wm + i * 16 + (l >> 4) * 4 + r;
            if ((l & 15) == 0) red[rowl][w & 3] = p;
        }
    __syncthreads();
    if (t < 64) {
        float s = red[t][0] + red[t][1] + red[t][2] + red[t][3];
        invr[t] = 1.0f / (sqrtf(s) + EPS);
    }
    __syncthreads();
    float* Ob = out + ((size_t)b * LQ + m0) * SD;
#pragma unroll
    for (int i = 0; i < 2; ++i)
#pragma unroll
        for (int r = 0; r < 4; ++r) {
            int rowl = wm + i * 16 + (l >> 4) * 4 + r;
            float iv = invr[rowl];
#pragma unroll
            for (int n = 0; n < 4; ++n) {
                int col = wn + n * 16 + (l & 15);
                Ob[(size_t)rowl * SD + col] = acc[i][n][r] * iv;
            }
        }
}

// =====================================================================
extern "C" void kernel_launch(void* const* d_in, const int* in_sizes, int n_in,
                              void* d_out, int out_size, void* d_ws, size_t ws_size,
                              hipStream_t stream)
{
    const float* query  = (const float*)d_in[0];
    const float* ctx    = (const float*)d_in[1];
    const float* mat    = (const float*)d_in[2];
    const float* W      = (const float*)d_in[3];
    const float* bias   = (const float*)d_in[4];
    const int*   smooth = (const int*)d_in[5];
    float* out = (float*)d_out;

    char* ws = (char*)d_ws;
    ushort* wctx   = (ushort*)ws;                                   // 32 MiB
    ushort* E      = (ushort*)(ws + (size_t)32 * 1024 * 1024);      //  8 MiB
    ushort* Wb     = (ushort*)(ws + (size_t)40 * 1024 * 1024);      // 0.5 MiB
    float*  rowssP = (float*)(ws + (size_t)(40 * 1024 + 512) * 1024); // 128 KiB

    wconv_kernel<<<dim3(SD * D / (256 * 8)), 256, 0, stream>>>(W, Wb);
    gemmA_kernel<<<dim3(256), 512, 0, stream>>>(query, mat, ctx, smooth, E);
    pv_kernel<<<dim3(256), 512, 0, stream>>>(E, ctx, wctx, rowssP);
    gemm3_kernel<<<dim3(2, B), 512, 0, stream>>>(wctx, query, rowssP, Wb, bias, out);
}